// Round 4
// baseline (825.342 us; speedup 1.0000x reference)
//
#include <hip/hip_runtime.h>
#include <hip/hip_bf16.h>

typedef __hip_bfloat16 bf16_t;
typedef __bf16 bf16x8 __attribute__((ext_vector_type(8)));
typedef float floatx4 __attribute__((ext_vector_type(4)));

#define DEVINL __device__ __forceinline__

DEVINL floatx4 mfma16(bf16x8 a, bf16x8 b, floatx4 c) {
  return __builtin_amdgcn_mfma_f32_16x16x32_bf16(a, b, c, 0, 0, 0);
}

// frag loaders: 8 contiguous elements -> bf16x8
DEVINL bf16x8 to_frag(const bf16_t* p) { return *(const bf16x8*)p; }
DEVINL bf16x8 to_frag(const float* p) {
  floatx4 a = *(const floatx4*)p;
  floatx4 b = *(const floatx4*)(p + 4);
  bf16x8 r;
#pragma unroll
  for (int i = 0; i < 4; i++) r[i] = (__bf16)a[i];
#pragma unroll
  for (int i = 0; i < 4; i++) r[4 + i] = (__bf16)b[i];
  return r;
}

template <class CT> DEVINL CT cvtC(float f);
template <> DEVINL bf16_t cvtC<bf16_t>(float f) { return __float2bfloat16(f); }
template <> DEVINL float cvtC<float>(float f) { return f; }

// ---------------------------------------------------------------------------
// C[M,N] = A[M,K] @ BT[N,K]^T   (A: fp32 or bf16; BT bf16; C fp32 or bf16)
// 128x128 tile, BK=32, 4 waves in 2x2, register-staged LDS.
// ---------------------------------------------------------------------------
template <class AT, class CT>
__global__ __launch_bounds__(256, 2) void gemm_bt(
    const AT* __restrict__ A, const bf16_t* __restrict__ BT,
    CT* __restrict__ C, int M, int N, int K) {
  __shared__ __align__(16) bf16_t a_lds[8 * 512];  // 8 m-tiles x (64 lanes x 8 bf16)
  __shared__ __align__(16) bf16_t b_lds[8 * 512];

  const int tid = threadIdx.x;
  const int wave = tid >> 6;
  const int lane = tid & 63;
  const int quad = lane >> 4;
  const int l16 = lane & 15;
  const int wm = wave >> 1, wn = wave & 1;

  const int row0 = blockIdx.y * 128;
  const int col0 = blockIdx.x * 128;

  floatx4 acc[4][4] = {};

  const AT* ag = A + (size_t)(row0 + wave * 32 + l16) * K + quad * 8;
  const bf16_t* bg = BT + (size_t)(col0 + wave * 32 + l16) * K + quad * 8;
  bf16_t* al = a_lds + wave * 1024 + lane * 8;
  bf16_t* bl = b_lds + wave * 1024 + lane * 8;

  for (int k0 = 0; k0 < K; k0 += 32) {
    bf16x8 av0 = to_frag(ag + k0);
    bf16x8 av1 = to_frag(ag + k0 + (size_t)16 * K);
    bf16x8 bv0 = to_frag(bg + k0);
    bf16x8 bv1 = to_frag(bg + k0 + (size_t)16 * K);
    __syncthreads();  // previous iteration's frag reads complete
    *(bf16x8*)al = av0;
    *(bf16x8*)(al + 512) = av1;
    *(bf16x8*)bl = bv0;
    *(bf16x8*)(bl + 512) = bv1;
    __syncthreads();  // LDS tile visible to all waves
    bf16x8 af[4], bfr[4];
#pragma unroll
    for (int i = 0; i < 4; i++)
      af[i] = *(const bf16x8*)(a_lds + (wm * 4 + i) * 512 + lane * 8);
#pragma unroll
    for (int j = 0; j < 4; j++)
      bfr[j] = *(const bf16x8*)(b_lds + (wn * 4 + j) * 512 + lane * 8);
#pragma unroll
    for (int i = 0; i < 4; i++)
#pragma unroll
      for (int j = 0; j < 4; j++)
        acc[i][j] = mfma16(af[i], bfr[j], acc[i][j]);
  }

#pragma unroll
  for (int i = 0; i < 4; i++)
#pragma unroll
    for (int j = 0; j < 4; j++)
#pragma unroll
      for (int r = 0; r < 4; r++) {
        int row = row0 + wm * 64 + i * 16 + quad * 4 + r;
        int col = col0 + wn * 64 + j * 16 + l16;
        C[(size_t)row * N + col] = cvtC<CT>(acc[i][j][r]);
      }
}

// ---------------------------------------------------------------------------
// out[N][M] = bf16(in[M][N]^T), in fp32, 32x32 LDS tiles
// ---------------------------------------------------------------------------
__global__ void transposecvt(const float* __restrict__ in,
                             bf16_t* __restrict__ out, int M, int N) {
  __shared__ bf16_t tile[32][33];
  int n0 = blockIdx.x * 32, m0 = blockIdx.y * 32;
  tile[threadIdx.y][threadIdx.x] =
      __float2bfloat16(in[(size_t)(m0 + threadIdx.y) * N + n0 + threadIdx.x]);
  __syncthreads();
  out[(size_t)(n0 + threadIdx.y) * M + m0 + threadIdx.x] =
      tile[threadIdx.x][threadIdx.y];
}

// ---------------------------------------------------------------------------
// VT[b,h,d,s] = qkv[b,s,2,h,d]   (per (b,h) 2048x128 -> 128x2048 transpose)
// ---------------------------------------------------------------------------
__global__ void transpose_v(const bf16_t* __restrict__ qkv,
                            bf16_t* __restrict__ VT) {
  __shared__ bf16_t tile[32][33];
  int bh = blockIdx.z;
  int b = bh >> 4, h = bh & 15;
  int s0 = blockIdx.x * 32, d0 = blockIdx.y * 32;
  tile[threadIdx.y][threadIdx.x] =
      qkv[(((size_t)(b * 2048 + s0 + threadIdx.y) * 3) + 2) * 2048 + h * 128 +
          d0 + threadIdx.x];
  __syncthreads();
  VT[((size_t)bh * 128 + d0 + threadIdx.y) * 2048 + s0 + threadIdx.x] =
      tile[threadIdx.x][threadIdx.y];
}

// ---------------------------------------------------------------------------
// RoPE on q,k IN-PLACE in qkv [B,S,3,H,hd]; q additionally scaled by hd^-0.5.
// cos/sin in fp32 (ref keeps them fp32). Thread: 4 (d,d+64) pairs of one
// (b,h,s). 2^20 threads.
// ---------------------------------------------------------------------------
__global__ void rope_qk(bf16_t* __restrict__ qkv) {
  struct __align__(8) bf4 { bf16_t v[4]; };
  int t = blockIdx.x * 256 + threadIdx.x;
  int dc = t & 15;
  int s = (t >> 4) & 2047;
  int h = (t >> 15) & 15;
  int b = t >> 19;
  int d = dc * 4;
  size_t base = ((size_t)(b * 2048 + s) * 3) * 2048 + h * 128;
  bf4 ql = *(const bf4*)(qkv + base + d);
  bf4 qh = *(const bf4*)(qkv + base + d + 64);
  bf4 kl = *(const bf4*)(qkv + base + 2048 + d);
  bf4 kh = *(const bf4*)(qkv + base + 2048 + d + 64);
  bf4 oql, oqh, okl, okh;
  const float scale = 0.08838834764831845f;  // 1/sqrt(128)
#pragma unroll
  for (int i = 0; i < 4; i++) {
    int j = d + i;
    float fr = (float)s * powf(10000.0f, -(float)j * (1.0f / 64.0f));
    float c = cosf(fr);
    float sn = sinf(fr);
    float qlo = __bfloat162float(ql.v[i]), qhi = __bfloat162float(qh.v[i]);
    float klo = __bfloat162float(kl.v[i]), khi = __bfloat162float(kh.v[i]);
    oql.v[i] = __float2bfloat16((qlo * c - qhi * sn) * scale);
    oqh.v[i] = __float2bfloat16((qhi * c + qlo * sn) * scale);
    okl.v[i] = __float2bfloat16(klo * c - khi * sn);
    okh.v[i] = __float2bfloat16(khi * c + klo * sn);
  }
  *(bf4*)(qkv + base + d) = oql;
  *(bf4*)(qkv + base + d + 64) = oqh;
  *(bf4*)(qkv + base + 2048 + d) = okl;
  *(bf4*)(qkv + base + 2048 + d + 64) = okh;
}

// ---------------------------------------------------------------------------
// Flash attention (non-causal). Grid (S/128, B*H), 256 threads.
// Wave w owns q-rows [w*32, w*32+32). Q pre-scaled+roped in qkv (stride 6144),
// K roped in qkv, V^T in [B,H,hd,S]. Out written as [B,S,H*hd] bf16.
// ---------------------------------------------------------------------------
__global__ __launch_bounds__(256, 2) void flash_attn(
    const bf16_t* __restrict__ qkv, const bf16_t* __restrict__ VT,
    bf16_t* __restrict__ Out) {
  const int S = 2048;
  const int RS = 6144;  // qkv row stride
  const int tid = threadIdx.x;
  const int wave = tid >> 6;
  const int lane = tid & 63;
  const int quad = lane >> 4;
  const int l16 = lane & 15;

  const int bh = blockIdx.y;
  const int q0 = blockIdx.x * 128;
  const int b = bh >> 4, h = bh & 15;

  const bf16_t* Qb = qkv + (size_t)b * S * RS + h * 128;
  const bf16_t* Kb = Qb + 2048;
  const bf16_t* Vb = VT + (size_t)bh * 128 * S;

  // per-wave P tile [32 q][128 k], stride 136 (272B = 17*16B: aligned, <=2-way banks)
  __shared__ __align__(16) bf16_t p_lds[4][32][136];

  bf16x8 qf[2][4];
#pragma unroll
  for (int i = 0; i < 2; i++)
#pragma unroll
    for (int ks = 0; ks < 4; ks++)
      qf[i][ks] = *(const bf16x8*)(Qb +
                                   (size_t)(q0 + wave * 32 + i * 16 + l16) * RS +
                                   ks * 32 + quad * 8);

  floatx4 o_acc[2][8] = {};
  float m_i[2][4], l_i[2][4];
#pragma unroll
  for (int i = 0; i < 2; i++)
#pragma unroll
    for (int r = 0; r < 4; r++) { m_i[i][r] = -3.0e38f; l_i[i][r] = 0.f; }

  for (int kt = 0; kt < S / 128; kt++) {
    const int kk0 = kt * 128;
    floatx4 s_acc[2][8] = {};
#pragma unroll
    for (int ks = 0; ks < 4; ks++)
#pragma unroll
      for (int nt = 0; nt < 8; nt++) {
        bf16x8 kf = *(const bf16x8*)(Kb + (size_t)(kk0 + nt * 16 + l16) * RS +
                                     ks * 32 + quad * 8);
        s_acc[0][nt] = mfma16(qf[0][ks], kf, s_acc[0][nt]);
        s_acc[1][nt] = mfma16(qf[1][ks], kf, s_acc[1][nt]);
      }

    // online softmax; row = i*16 + quad*4 + r, cols spread over l16 x nt
#pragma unroll
    for (int i = 0; i < 2; i++)
#pragma unroll
      for (int r = 0; r < 4; r++) {
        float mx = s_acc[i][0][r];
#pragma unroll
        for (int nt = 1; nt < 8; nt++) mx = fmaxf(mx, s_acc[i][nt][r]);
#pragma unroll
        for (int off = 1; off < 16; off <<= 1)
          mx = fmaxf(mx, __shfl_xor(mx, off, 64));
        float mnew = fmaxf(m_i[i][r], mx);
        float alpha = __expf(m_i[i][r] - mnew);
        m_i[i][r] = mnew;
        float rs = 0.f;
#pragma unroll
        for (int nt = 0; nt < 8; nt++) {
          float p = __expf(s_acc[i][nt][r] - mnew);
          s_acc[i][nt][r] = p;
          rs += p;
        }
#pragma unroll
        for (int off = 1; off < 16; off <<= 1) rs += __shfl_xor(rs, off, 64);
        l_i[i][r] = l_i[i][r] * alpha + rs;
#pragma unroll
        for (int dt = 0; dt < 8; dt++) o_acc[i][dt][r] *= alpha;
      }

    // P (C-layout regs) -> LDS row-major (per-wave region)
#pragma unroll
    for (int i = 0; i < 2; i++)
#pragma unroll
      for (int nt = 0; nt < 8; nt++)
#pragma unroll
        for (int r = 0; r < 4; r++)
          p_lds[wave][i * 16 + quad * 4 + r][nt * 16 + l16] =
              __float2bfloat16(s_acc[i][nt][r]);

    // Fence: vector ds_reads must not be hoisted above the scalar ds_writes.
    __syncthreads();

    // PV: A-frags from LDS, B-frags (V) straight from global VT
#pragma unroll
    for (int ks = 0; ks < 4; ks++) {
      bf16x8 pf0 = *(const bf16x8*)&p_lds[wave][l16][ks * 32 + quad * 8];
      bf16x8 pf1 = *(const bf16x8*)&p_lds[wave][16 + l16][ks * 32 + quad * 8];
#pragma unroll
      for (int dt = 0; dt < 8; dt++) {
        bf16x8 vf = *(const bf16x8*)(Vb + (size_t)(dt * 16 + l16) * S + kk0 +
                                     ks * 32 + quad * 8);
        o_acc[0][dt] = mfma16(pf0, vf, o_acc[0][dt]);
        o_acc[1][dt] = mfma16(pf1, vf, o_acc[1][dt]);
      }
    }
    // Fence: next iteration's P-writes must not pass these reads.
    __syncthreads();
  }

#pragma unroll
  for (int i = 0; i < 2; i++)
#pragma unroll
    for (int r = 0; r < 4; r++) {
      float inv = 1.f / l_i[i][r];
      int s = q0 + wave * 32 + i * 16 + quad * 4 + r;
#pragma unroll
      for (int dt = 0; dt < 8; dt++)
        Out[((size_t)b * S + s) * 2048 + h * 128 + dt * 16 + l16] =
            __float2bfloat16(o_acc[i][dt][r] * inv);
    }
}

// ---------------------------------------------------------------------------
extern "C" void kernel_launch(void* const* d_in, const int* in_sizes, int n_in,
                              void* d_out, int out_size, void* d_ws,
                              size_t ws_size, hipStream_t stream) {
  // Reference setup_inputs builds float32 arrays -> inputs/outputs are fp32.
  const float* x = (const float*)d_in[0];
  const float* w_qkv = (const float*)d_in[1];
  const float* w_out = (const float*)d_in[2];
  float* out = (float*)d_out;
  char* ws = (char*)d_ws;

  const int B = 2, S = 2048, D = 2048;
  // ws layout (total 92.3 MB, all bf16):
  //   [0, 50.3MB)        qkv   — dead after flash_attn, then reused for woutT
  //   [50.3, 75.5MB)     wqkvT — dead after QKV GEMM, then reused for attn
  //   [75.5, 92.3MB)     VT
  bf16_t* qkv = (bf16_t*)(ws);
  bf16_t* wqkvT = (bf16_t*)(ws + (size_t)B * S * 3 * D * 2);
  bf16_t* VT = (bf16_t*)(ws + (size_t)B * S * 3 * D * 2 + (size_t)3 * D * D * 2);
  bf16_t* attn = wqkvT;   // wqkvT dead after QKV GEMM (16.8 <= 25.2 MB)
  bf16_t* woutT = qkv;    // qkv dead after flash_attn (8.4 <= 50.3 MB)

  dim3 b32(32, 32);
  transposecvt<<<dim3(3 * D / 32, D / 32), b32, 0, stream>>>(w_qkv, wqkvT, D, 3 * D);
  gemm_bt<float, bf16_t><<<dim3(3 * D / 128, B * S / 128), 256, 0, stream>>>(
      x, wqkvT, qkv, B * S, 3 * D, D);
  rope_qk<<<4096, 256, 0, stream>>>(qkv);
  transpose_v<<<dim3(S / 32, 4, B * 16), b32, 0, stream>>>(qkv, VT);
  flash_attn<<<dim3(S / 128, B * 16), 256, 0, stream>>>(qkv, VT, attn);
  transposecvt<<<dim3(D / 32, D / 32), b32, 0, stream>>>(w_out, woutT, D, D);
  gemm_bt<bf16_t, float><<<dim3(D / 128, B * S / 128), 256, 0, stream>>>(
      attn, woutT, out, B * S, D, D);
}